// Round 10
// baseline (6204.963 us; speedup 1.0000x reference)
//
#include <hip/hip_runtime.h>
#include <stdint.h>

#define Bn 64
#define Tn 2048
#define Dn 64
#define H1n 256
#define H2n 128
#define G1n 768
#define G2n 384
#define CH 256              // time-chunk length
#define NCH (Tn / CH)       // 8 chunks

typedef _Float16 f16;
typedef f16 f16x2 __attribute__((ext_vector_type(2)));

#if defined(__HIP_DEVICE_COMPILE__) && __has_builtin(__builtin_amdgcn_fdot2)
#define USE_FDOT2 1
#endif

static __device__ __forceinline__ float fdot2(uint32_t a, uint32_t b, float c){
#ifdef USE_FDOT2
  return __builtin_amdgcn_fdot2(__builtin_bit_cast(f16x2, a), __builtin_bit_cast(f16x2, b), c, false);
#else
  f16x2 av = __builtin_bit_cast(f16x2, a), bv = __builtin_bit_cast(f16x2, b);
  return c + (float)av[0]*(float)bv[0] + (float)av[1]*(float)bv[1];
#endif
}

static __device__ __forceinline__ uint32_t packf2(float a, float b){
  unsigned short lo = __builtin_bit_cast(unsigned short, (f16)a);
  unsigned short hi = __builtin_bit_cast(unsigned short, (f16)b);
  return (uint32_t)lo | ((uint32_t)hi << 16);
}
static __device__ __forceinline__ float h2f(unsigned short s){
  return (float)__builtin_bit_cast(f16, s);
}
static __device__ __forceinline__ unsigned short f2h(float a){
  return __builtin_bit_cast(unsigned short, (f16)a);
}

static __device__ __forceinline__ float rcpf_(float x){
#if defined(__HIP_DEVICE_COMPILE__) && __has_builtin(__builtin_amdgcn_rcpf)
  return __builtin_amdgcn_rcpf(x);
#else
  return 1.0f/x;
#endif
}
static __device__ __forceinline__ float sigm_(float x){ return rcpf_(1.0f + __expf(-x)); }
static __device__ __forceinline__ float tanh_(float x){ return 1.0f - 2.0f*rcpf_(1.0f + __expf(2.0f*x)); }

// 4 dot2s: pairs (w[wb+k], v.comp[k])
#define D4(acc0, acc1, wb, v) \
  acc0 = fdot2(w[(wb)+0], (v).x, acc0); acc1 = fdot2(w[(wb)+1], (v).y, acc1); \
  acc0 = fdot2(w[(wb)+2], (v).z, acc0); acc1 = fdot2(w[(wb)+3], (v).w, acc1);

// keep per-thread weight array alive in VGPRs (safe only when under the reg cap)
#define PIN(arr, n) _Pragma("unroll") for (int _p = 0; _p < (n); ++_p) asm volatile("" : "+v"((arr)[_p]));

// ---------------- prep kernels ----------------

__global__ void pack_x16_kernel(const float* __restrict__ x, uint32_t* __restrict__ x16){
  int stride = gridDim.x * blockDim.x;
  for (int i = blockIdx.x*blockDim.x + threadIdx.x; i < Bn*Tn*Dn/2; i += stride){
    float2 v = ((const float2*)x)[i];
    x16[i] = packf2(v.x, v.y);
  }
}

__global__ void pack_w_kernel(const float* __restrict__ Wih1, const float* __restrict__ Whh1,
                              const float* __restrict__ Wih2, const float* __restrict__ Whh2,
                              const float* __restrict__ bih2,
                              const float* __restrict__ g1, const float* __restrict__ be1,
                              const float* __restrict__ m1, const float* __restrict__ v1,
                              uint32_t* __restrict__ wih1p, uint32_t* __restrict__ whh1p,
                              uint32_t* __restrict__ wih2p, uint32_t* __restrict__ whh2p,
                              float* __restrict__ b2p)
{
  const int NA = 98304, NB = 24576, NC = 49152, ND = 24576, NE = 384;
  int i = blockIdx.x*blockDim.x + threadIdx.x;
  if (i < NA){
    // gru1 weights (1024-thread layout): [j=0..95][tid=0..1023]
    // thread(q=tid>>8 in 0..3, u=tid&255); j = g*32 + c (g=gate 0..2, c=colpair 0..31)
    // row = u + 256*g, col = 64*q + 2c
    int j = i >> 10, t = i & 1023;
    int q = t >> 8, u = t & 255;
    int g = j >> 5, c = j & 31;
    int row = u + (g << 8);
    int col = (q << 6) + (c << 1);
    whh1p[i] = packf2(Whh1[row*256+col], Whh1[row*256+col+1]);
  } else if (i < NA+NB){
    // gemm1 weights: [j=0..31][g=0..767]; pairs cols (2j,2j+1) of row g
    int d = i - NA;
    int j = d / 768, g = d % 768;
    wih1p[d] = packf2(Wih1[g*64 + 2*j], Wih1[g*64 + 2*j + 1]);
  } else if (i < NA+NB+NC){
    // gemm2 weights, BN1 scale folded: [j=0..127][g=0..383]
    int d = i - NA - NB;
    int j = d / 384, g = d % 384;
    int k0 = 2*j;
    float sa = g1[k0]   * rsqrtf(v1[k0]   + 1e-5f);
    float sb = g1[k0+1] * rsqrtf(v1[k0+1] + 1e-5f);
    wih2p[d] = packf2(Wih2[g*256+k0]*sa, Wih2[g*256+k0+1]*sb);
  } else if (i < NA+NB+NC+ND){
    // gru2 weights: [j=0..47][tid=0..511]; thread(q=tid>>7,u=tid&127)
    // row = u + 128*(j/16), colpair c = j%16, col = 32*q + 2c
    int d = i - NA - NB - NC;
    int j = d >> 9, t = d & 511;
    int q = t >> 7, u = t & 127;
    int ri = j >> 4, c = j & 15;
    int row = u + (ri << 7);
    int col = (q << 5) + (c << 1);
    whh2p[d] = packf2(Whh2[row*128+col], Whh2[row*128+col+1]);
  } else if (i < NA+NB+NC+ND+NE){
    // folded bias: b2p[g] = b_ih2[g] + sum_k W_ih2[g,k]*(beta1[k]-mean1[k]*s1[k])
    int g = i - NA - NB - NC - ND;
    float acc = bih2[g];
    for (int k = 0; k < 256; ++k){
      float s = g1[k]*rsqrtf(v1[k]+1e-5f);
      float tsh = be1[k] - m1[k]*s;
      acc += Wih2[g*256+k]*tsh;
    }
    b2p[g] = acc;
  }
}

// ---------------- input-projection GEMMs (per time-chunk) ----------------

__global__ __launch_bounds__(768) __attribute__((amdgpu_waves_per_eu(2,2)))
void gemm1_kernel(const uint32_t* __restrict__ x16,
    const uint32_t* __restrict__ wp, const float* __restrict__ bih1,
    unsigned short* __restrict__ gxc, int t0)
{
  const int g = threadIdx.x;
  uint32_t w[32];
#pragma unroll
  for (int j = 0; j < 32; ++j) w[j] = wp[j*768 + g];
  PIN(w, 32)
  const float bias = bih1[g];
  const int r0 = blockIdx.x * 64;            // 256 blocks x 64 rows = 16384 = Bn*CH
  for (int r = r0; r < r0 + 64; ++r){
    int b = r >> 8, tl = r & (CH-1);
    const uint4* xr = (const uint4*)(x16 + ((size_t)(b*Tn + t0 + tl))*32);
    float a0 = 0.f, a1 = 0.f;
#pragma unroll
    for (int i = 0; i < 8; ++i){
      uint4 v = xr[i];
      D4(a0, a1, i*4, v);
    }
    gxc[(size_t)r*G1n + g] = f2h(bias + a0 + a1);
  }
}

// gemm2: 512 blocks x 32 rows. Thread = output col g (384 threads).
// h1 tile staged in LDS (broadcast reads); weights streamed in 8-dword chunks
// from L2 (hot, shared across blocks); acc[32] static-indexed. ~63 regs fits
// any observed cap. (r9 measurement: saved ~53us/chunk vs w[128] variant.)
#define G2R 32
__global__ __launch_bounds__(384)
void gemm2_kernel(const unsigned short* __restrict__ h1c,
    const uint32_t* __restrict__ wp, const float* __restrict__ b2p,
    unsigned short* __restrict__ gx2c)
{
  __shared__ __align__(16) uint32_t hl[G2R*128];   // 32 rows x 256 fp16 = 16 KB
  const int g = threadIdx.x;
  const int r0 = blockIdx.x * G2R;                 // 512 blocks
  const uint32_t* h32 = (const uint32_t*)h1c;
  for (int i = g; i < G2R*128; i += 384)
    hl[i] = h32[(size_t)r0*128 + i];
  __syncthreads();

  float acc[G2R];
#pragma unroll
  for (int r = 0; r < G2R; ++r) acc[r] = 0.f;

  for (int jc = 0; jc < 16; ++jc){                 // 16 chunks x 8 dwords (16 k)
    uint32_t w8[8];
#pragma unroll
    for (int i = 0; i < 8; ++i) w8[i] = wp[(jc*8+i)*384 + g];
#pragma unroll
    for (int r = 0; r < G2R; ++r){
      const uint4* hv = (const uint4*)(hl + r*128 + jc*8);
      uint4 v0 = hv[0], v1 = hv[1];
      float a = acc[r];
      a = fdot2(w8[0], v0.x, a); a = fdot2(w8[1], v0.y, a);
      a = fdot2(w8[2], v0.z, a); a = fdot2(w8[3], v0.w, a);
      a = fdot2(w8[4], v1.x, a); a = fdot2(w8[5], v1.y, a);
      a = fdot2(w8[6], v1.z, a); a = fdot2(w8[7], v1.w, a);
      acc[r] = a;
    }
  }
  const float bias = b2p[g];
#pragma unroll
  for (int r = 0; r < G2R; ++r)
    gx2c[(size_t)(r0+r)*G2n + g] = f2h(bias + acc[r]);
}

// ---------------- persistent GRU layer 1 (one chunk) ----------------
// 64 WGs (one per batch), 1024 threads: q=tid>>8 col-quarter (64 cols), u=tid&255.
// Thread owns rows {u,u+256,u+512} x 64 cols = 96 weight dwords — ALL of Whh1
// register-resident across the WG (1024 x 96 dw = 393 KB).
// RA model (r2/r7/r8/r9): VGPR target = 512/(achievable waves/SIMD), default-capped
// at 128. LDS padded to 82 KB -> exactly 1 WG/CU -> 16 waves/CU = 4 waves/SIMD ->
// target 128 >= 96+~29 temps -> no sinking. (r7's failure: small LDS let 2 WGs
// co-reside -> target 64 -> spills. No PIN: PIN under a tight budget = spills.)

__global__ __launch_bounds__(1024)
void gru1_kernel(
    const unsigned short* __restrict__ gxc, const uint32_t* __restrict__ wp,
    const float* __restrict__ bhh, unsigned short* __restrict__ h1c,
    float* __restrict__ hs1, int t0)
{
  __shared__ __align__(16) uint32_t h16[128];   // 256 fp16 h values
  __shared__ float part[20480];                 // [0..2303] used; pads LDS to 82.4KB
  const int tid = threadIdx.x;
  const int q = tid >> 8, u = tid & 255;
  const int b = blockIdx.x;

  uint32_t w[96];
#pragma unroll
  for (int j = 0; j < 96; ++j) w[j] = wp[j*1024 + tid];

  float h = 0.f, bhr = 0.f, bhz = 0.f, bhn = 0.f, gxr = 0.f, gxz = 0.f, gxn = 0.f;
  const unsigned short* gp = gxc + (size_t)b*CH*G1n;
  unsigned short* h1p = h1c + (size_t)b*CH*H1n + u;
  if (q == 0){
    if (t0 > 0) h = hs1[b*H1n + u];
    ((unsigned short*)h16)[u] = f2h(h);
    bhr = bhh[u]; bhz = bhh[u+256]; bhn = bhh[u+512];
    gxr = h2f(gp[u]); gxz = h2f(gp[u+256]); gxn = h2f(gp[u+512]);
  }
  __syncthreads();

  const uint4* hh4 = (const uint4*)(h16 + (q << 5));  // 32 dwords = 64 cols/quarter
  for (int t = 0; t < CH; ++t){
    float ar0=0,ar1=0,az0=0,az1=0,an0=0,an1=0;
#pragma unroll
    for (int ch = 0; ch < 8; ++ch){
      const uint4 v = hh4[ch];
      D4(ar0,ar1, ch*4,      v);
      D4(az0,az1, 32+ch*4,   v);
      D4(an0,an1, 64+ch*4,   v);
    }
    if (q > 0){
      int o = (q-1)*768;
      part[o+u]     = ar0 + ar1;
      part[o+u+256] = az0 + az1;
      part[o+u+512] = an0 + an1;
    }
    __syncthreads();
    if (q == 0){
      float ghr = ar0+ar1 + part[u]     + part[768+u]     + part[1536+u]     + bhr;
      float ghz = az0+az1 + part[u+256] + part[768+u+256] + part[1536+u+256] + bhz;
      float ghn = an0+an1 + part[u+512] + part[768+u+512] + part[1536+u+512] + bhn;
      float r = sigm_(gxr + ghr);
      float z = sigm_(gxz + ghz);
      float n = tanh_(gxn + r*ghn);
      h = n + z*(h - n);                       // (1-z)*n + z*h
      ((unsigned short*)h16)[u] = f2h(h);
      *h1p = f2h(h); h1p += H1n;
      if (t + 1 < CH){
        const unsigned short* gnx = gp + (size_t)(t+1)*G1n;
        gxr = h2f(gnx[u]); gxz = h2f(gnx[u+256]); gxn = h2f(gnx[u+512]);
      }
    }
    __syncthreads();
  }
  if (q == 0) hs1[b*H1n + u] = h;
}

// ---------------- persistent GRU layer 2 + BN2 + maxpool + tanh + FC (one chunk) ----
// 64 WGs, 512 threads: q=tid>>7 col-quarter, u=tid&127 hidden unit. w[48] mostly
// fits observed caps -> plain round-2 form (verified fastest of the variants tried).

__global__ __launch_bounds__(512) __attribute__((amdgpu_waves_per_eu(2,2)))
void gru2_kernel(
    const unsigned short* __restrict__ gx2c, const uint32_t* __restrict__ wp,
    const float* __restrict__ bhh2,
    const float* __restrict__ g2, const float* __restrict__ be2,
    const float* __restrict__ m2, const float* __restrict__ v2,
    const float* __restrict__ fcw, const float* __restrict__ fcb,
    float* __restrict__ out, float* __restrict__ hs2, float* __restrict__ ms2, int t0)
{
  __shared__ __align__(16) uint32_t h16[64];    // 128 fp16 h values
  __shared__ float part[1152];                  // q=1..3 partials per row
  __shared__ float thb[128];
  const int tid = threadIdx.x;
  const int q = tid >> 7, u = tid & 127;
  const int b = blockIdx.x;

  uint32_t w[48];
#pragma unroll
  for (int j = 0; j < 48; ++j) w[j] = wp[j*512 + tid];

  float h = 0.f, m = -3.0e38f;
  float bhr=0,bhz=0,bhn=0, gxr=0,gxz=0,gxn=0, s2=0.f, t2=0.f;
  const unsigned short* gp = gx2c + (size_t)b*CH*G2n;
  if (q == 0){
    if (t0 > 0){ h = hs2[b*H2n + u]; m = ms2[b*H2n + u]; }
    ((unsigned short*)h16)[u] = f2h(h);
    bhr = bhh2[u]; bhz = bhh2[u+128]; bhn = bhh2[u+256];
    s2 = g2[u]*rsqrtf(v2[u]+1e-5f);
    t2 = be2[u] - m2[u]*s2;
    gxr = h2f(gp[u]); gxz = h2f(gp[u+128]); gxn = h2f(gp[u+256]);
  }
  __syncthreads();

  const uint32_t* hh = h16 + (q << 4);
  for (int t = 0; t < CH; ++t){
    const uint4 v0  = ((const uint4*)hh)[0];
    const uint4 v1  = ((const uint4*)hh)[1];
    const uint4 v2_ = ((const uint4*)hh)[2];
    const uint4 v3  = ((const uint4*)hh)[3];
    float a00=0,a01=0,a10=0,a11=0,a20=0,a21=0;
    D4(a00,a01, 0, v0); D4(a00,a01, 4, v1); D4(a00,a01, 8, v2_); D4(a00,a01,12, v3);
    D4(a10,a11,16, v0); D4(a10,a11,20, v1); D4(a10,a11,24, v2_); D4(a10,a11,28, v3);
    D4(a20,a21,32, v0); D4(a20,a21,36, v1); D4(a20,a21,40, v2_); D4(a20,a21,44, v3);
    if (q > 0){
      int o = (q-1)*384;
      part[o+u]     = a00 + a01;
      part[o+u+128] = a10 + a11;
      part[o+u+256] = a20 + a21;
    }
    __syncthreads();
    if (q == 0){
      float ghr = a00+a01 + part[u]     + part[384+u]     + part[768+u]     + bhr;
      float ghz = a10+a11 + part[u+128] + part[384+u+128] + part[768+u+128] + bhz;
      float ghn = a20+a21 + part[u+256] + part[384+u+256] + part[768+u+256] + bhn;
      float r = sigm_(gxr + ghr);
      float z = sigm_(gxz + ghz);
      float n = tanh_(gxn + r*ghn);
      h = n + z*(h - n);
      float val = s2*h + t2;               // eval-mode BN2
      m = fmaxf(m, val);                   // global max pool over time
      ((unsigned short*)h16)[u] = f2h(h);
      if (t + 1 < CH){
        const unsigned short* gnx = gp + (size_t)(t+1)*G2n;
        gxr = h2f(gnx[u]); gxz = h2f(gnx[u+128]); gxn = h2f(gnx[u+256]);
      }
    }
    __syncthreads();
  }
  if (q == 0){ hs2[b*H2n + u] = h; ms2[b*H2n + u] = m; }

  if (t0 + CH == Tn){                      // last chunk: fused epilogue
    if (q == 0) thb[u] = tanh_(m);
    __syncthreads();
    if (tid < 10){
      float a = fcb[tid];
      for (int k = 0; k < 128; ++k) a += thb[k]*fcw[tid*128+k];
      out[b*10 + tid] = a;
    }
  }
}

// ---------------- launch ----------------

extern "C" void kernel_launch(void* const* d_in, const int* in_sizes, int n_in,
                              void* d_out, int out_size, void* d_ws, size_t ws_size,
                              hipStream_t stream)
{
  const float* x    = (const float*)d_in[0];
  const float* Wih1 = (const float*)d_in[1];
  const float* Whh1 = (const float*)d_in[2];
  const float* bih1 = (const float*)d_in[3];
  const float* bhh1 = (const float*)d_in[4];
  const float* g1   = (const float*)d_in[5];
  const float* be1  = (const float*)d_in[6];
  const float* m1   = (const float*)d_in[7];
  const float* v1   = (const float*)d_in[8];
  const float* Wih2 = (const float*)d_in[9];
  const float* Whh2 = (const float*)d_in[10];
  const float* bih2 = (const float*)d_in[11];
  const float* bhh2 = (const float*)d_in[12];
  const float* g2   = (const float*)d_in[13];
  const float* be2  = (const float*)d_in[14];
  const float* m2   = (const float*)d_in[15];
  const float* v2   = (const float*)d_in[16];
  const float* fcw  = (const float*)d_in[17];
  const float* fcb  = (const float*)d_in[18];
  float* out = (float*)d_out;
  char* ws = (char*)d_ws;

  // workspace layout (bytes) — total ~63.8 MB
  uint32_t* whh1p = (uint32_t*)(ws + 0);          // 98304 dw  = 393216 B
  uint32_t* wih1p = (uint32_t*)(ws + 393216);     // 24576 dw  =  98304 B
  uint32_t* wih2p = (uint32_t*)(ws + 491520);     // 49152 dw  = 196608 B
  uint32_t* whh2p = (uint32_t*)(ws + 688128);     // 24576 dw  =  98304 B
  float*    b2p   = (float*)   (ws + 786432);     // 384 f32   (pad to 1536 B)
  float*    hs1   = (float*)   (ws + 787968);     // 16384 f32 =  65536 B
  float*    hs2   = (float*)   (ws + 853504);     //  8192 f32 =  32768 B
  float*    ms2   = (float*)   (ws + 886272);     //  8192 f32 =  32768 B
  uint32_t* x16   = (uint32_t*)(ws + 919040);     // 4194304 dw = 16777216 B
  unsigned short* gx1c = (unsigned short*)(ws + 17696256);  // 64*256*768 h = 25165824 B
  unsigned short* h1c  = (unsigned short*)(ws + 42862080);  // 64*256*256 h =  8388608 B
  unsigned short* gx2c = (unsigned short*)(ws + 51250688);  // 64*256*384 h = 12582912 B

  pack_x16_kernel<<<2048, 256, 0, stream>>>(x, x16);
  pack_w_kernel<<<770, 256, 0, stream>>>(Wih1, Whh1, Wih2, Whh2, bih2, g1, be1, m1, v1,
                                         wih1p, whh1p, wih2p, whh2p, b2p);
  for (int c = 0; c < NCH; ++c){
    int t0 = c * CH;
    gemm1_kernel<<<256, 768, 0, stream>>>(x16, wih1p, bih1, gx1c, t0);
    gru1_kernel<<<64, 1024, 0, stream>>>(gx1c, whh1p, bhh1, h1c, hs1, t0);
    gemm2_kernel<<<512, 384, 0, stream>>>(h1c, wih2p, b2p, gx2c);
    gru2_kernel<<<64, 512, 0, stream>>>(gx2c, whh2p, bhh2, g2, be2, m2, v2,
                                        fcw, fcb, out, hs2, ms2, t0);
  }
}

// Round 11
// 3087.469 us; speedup vs baseline: 2.0097x; 2.0097x over previous
//
#include <hip/hip_runtime.h>
#include <stdint.h>

#define Bn 64
#define Tn 2048
#define Dn 64
#define H1n 256
#define H2n 128
#define G1n 768
#define G2n 384
#define CH 128              // time-chunk length
#define NCH (Tn / CH)       // 16 chunks

typedef _Float16 f16;
typedef f16 f16x2 __attribute__((ext_vector_type(2)));

#if defined(__HIP_DEVICE_COMPILE__) && __has_builtin(__builtin_amdgcn_fdot2)
#define USE_FDOT2 1
#endif

static __device__ __forceinline__ float fdot2(uint32_t a, uint32_t b, float c){
#ifdef USE_FDOT2
  return __builtin_amdgcn_fdot2(__builtin_bit_cast(f16x2, a), __builtin_bit_cast(f16x2, b), c, false);
#else
  f16x2 av = __builtin_bit_cast(f16x2, a), bv = __builtin_bit_cast(f16x2, b);
  return c + (float)av[0]*(float)bv[0] + (float)av[1]*(float)bv[1];
#endif
}

static __device__ __forceinline__ uint32_t packf2(float a, float b){
  unsigned short lo = __builtin_bit_cast(unsigned short, (f16)a);
  unsigned short hi = __builtin_bit_cast(unsigned short, (f16)b);
  return (uint32_t)lo | ((uint32_t)hi << 16);
}
static __device__ __forceinline__ float h2f(unsigned short s){
  return (float)__builtin_bit_cast(f16, s);
}
static __device__ __forceinline__ unsigned short f2h(float a){
  return __builtin_bit_cast(unsigned short, (f16)a);
}

static __device__ __forceinline__ float rcpf_(float x){
#if defined(__HIP_DEVICE_COMPILE__) && __has_builtin(__builtin_amdgcn_rcpf)
  return __builtin_amdgcn_rcpf(x);
#else
  return 1.0f/x;
#endif
}
static __device__ __forceinline__ float sigm_(float x){ return rcpf_(1.0f + __expf(-x)); }
static __device__ __forceinline__ float tanh_(float x){ return 1.0f - 2.0f*rcpf_(1.0f + __expf(2.0f*x)); }

// 4 dot2s: pairs (w[wb+k], v.comp[k])
#define D4(acc0, acc1, wb, v) \
  acc0 = fdot2(w[(wb)+0], (v).x, acc0); acc1 = fdot2(w[(wb)+1], (v).y, acc1); \
  acc0 = fdot2(w[(wb)+2], (v).z, acc0); acc1 = fdot2(w[(wb)+3], (v).w, acc1);

// ---------------- prep kernels ----------------

__global__ void pack_x16_kernel(const float* __restrict__ x, uint32_t* __restrict__ x16){
  int stride = gridDim.x * blockDim.x;
  for (int i = blockIdx.x*blockDim.x + threadIdx.x; i < Bn*Tn*Dn/2; i += stride){
    float2 v = ((const float2*)x)[i];
    x16[i] = packf2(v.x, v.y);
  }
}

__global__ void pack_w_kernel(const float* __restrict__ Wih1, const float* __restrict__ Whh1,
                              const float* __restrict__ Wih2, const float* __restrict__ Whh2,
                              const float* __restrict__ bih2,
                              const float* __restrict__ g1, const float* __restrict__ be1,
                              const float* __restrict__ m1, const float* __restrict__ v1,
                              uint32_t* __restrict__ wih1p, uint32_t* __restrict__ whh1p,
                              uint32_t* __restrict__ wih2p, uint32_t* __restrict__ whh2p,
                              float* __restrict__ b2p)
{
  const int NA = 98304, NB = 24576, NC = 49152, ND = 24576, NE = 384;
  int i = blockIdx.x*blockDim.x + threadIdx.x;
  if (i < NA){
    // gru1 weights: [j=0..191][tid=0..511]; thread(q=tid>>8,u=tid&255)
    // row = u + 256*(j/64), colpair c = j%64, col = 128*q + 2c
    int j = i >> 9, t = i & 511;
    int q = t >> 8, u = t & 255;
    int ri = j >> 6, c = j & 63;
    int row = u + (ri << 8);
    int col = (q << 7) + (c << 1);
    whh1p[i] = packf2(Whh1[row*256+col], Whh1[row*256+col+1]);
  } else if (i < NA+NB){
    // gemm1 weights: [j=0..31][g=0..767]; pairs cols (2j,2j+1) of row g
    int d = i - NA;
    int j = d / 768, g = d % 768;
    wih1p[d] = packf2(Wih1[g*64 + 2*j], Wih1[g*64 + 2*j + 1]);
  } else if (i < NA+NB+NC){
    // gemm2 weights, BN1 scale folded: [j=0..127][g=0..383]
    int d = i - NA - NB;
    int j = d / 384, g = d % 384;
    int k0 = 2*j;
    float sa = g1[k0]   * rsqrtf(v1[k0]   + 1e-5f);
    float sb = g1[k0+1] * rsqrtf(v1[k0+1] + 1e-5f);
    wih2p[d] = packf2(Wih2[g*256+k0]*sa, Wih2[g*256+k0+1]*sb);
  } else if (i < NA+NB+NC+ND){
    // gru2 weights: [j=0..47][tid=0..511]; thread(q=tid>>7,u=tid&127)
    // row = u + 128*(j/16), colpair c = j%16, col = 32*q + 2c
    int d = i - NA - NB - NC;
    int j = d >> 9, t = d & 511;
    int q = t >> 7, u = t & 127;
    int ri = j >> 4, c = j & 15;
    int row = u + (ri << 7);
    int col = (q << 5) + (c << 1);
    whh2p[d] = packf2(Whh2[row*128+col], Whh2[row*128+col+1]);
  } else if (i < NA+NB+NC+ND+NE){
    // folded bias: b2p[g] = b_ih2[g] + sum_k W_ih2[g,k]*(beta1[k]-mean1[k]*s1[k])
    int g = i - NA - NB - NC - ND;
    float acc = bih2[g];
    for (int k = 0; k < 256; ++k){
      float s = g1[k]*rsqrtf(v1[k]+1e-5f);
      float tsh = be1[k] - m1[k]*s;
      acc += Wih2[g*256+k]*tsh;
    }
    b2p[g] = acc;
  }
}

// ---------------- standalone gemm1 (prologue for chunk 0 only) ----------------

__global__ __launch_bounds__(768)
void gemm1_kernel(const uint32_t* __restrict__ x16,
    const uint32_t* __restrict__ wp, const float* __restrict__ bih1,
    unsigned short* __restrict__ gxc, int t0)
{
  const int g = threadIdx.x;
  uint32_t w[32];
#pragma unroll
  for (int j = 0; j < 32; ++j) w[j] = wp[j*768 + g];
  const float bias = bih1[g];
  const int r0 = blockIdx.x * 64;            // 128 blocks x 64 rows = 8192 = Bn*CH
  for (int r = r0; r < r0 + 64; ++r){
    int b = r >> 7, tl = r & (CH-1);
    const uint4* xr = (const uint4*)(x16 + ((size_t)(b*Tn + t0 + tl))*32);
    float a0 = 0.f, a1 = 0.f;
#pragma unroll
    for (int i = 0; i < 8; ++i){
      uint4 v = xr[i];
      D4(a0, a1, i*4, v);
    }
    gxc[(size_t)r*G1n + g] = f2h(bias + a0 + a1);
  }
}

// ---------------- fused pipeline stage ----------------
// One launch per chunk index c (0..NCH). 192 blocks, 512 threads:
//   blocks   0..63 : gru1(chunk c)          [r2-proven form, ~155us critical path]
//   blocks  64..127: gemm2+gru2(chunk c-1)  [gx2 kept in LDS, ~45us]
//   blocks 128..191: gemm1(chunk c+1)       [~7us]
// Branches are data-independent (double-buffered gx1/h1); 112KB static LDS
// forces 1 WG/CU so heavy blocks never share a CU (straggler control, r8-verified
// benign for the gru1 branch).

__global__ __launch_bounds__(512)
void fused_kernel(const uint32_t* __restrict__ x16,
    const uint32_t* __restrict__ wih1p, const float* __restrict__ bih1,
    const unsigned short* __restrict__ gx1R, unsigned short* __restrict__ gx1W,
    const uint32_t* __restrict__ whh1p, const float* __restrict__ bhh1,
    unsigned short* __restrict__ h1W, const unsigned short* __restrict__ h1R,
    float* __restrict__ hs1,
    const uint32_t* __restrict__ wih2p, const float* __restrict__ b2p,
    const uint32_t* __restrict__ whh2p, const float* __restrict__ bhh2,
    const float* __restrict__ g2, const float* __restrict__ be2,
    const float* __restrict__ m2, const float* __restrict__ v2,
    const float* __restrict__ fcw, const float* __restrict__ fcb,
    float* __restrict__ out, float* __restrict__ hs2, float* __restrict__ ms2,
    int c)
{
  __shared__ __align__(16) uint32_t smem[28672];   // 112 KB -> 1 WG/CU
  const int blk = blockIdx.x;
  const int tid = threadIdx.x;

  if (blk < 64){
    // ================= branch A: gru1 chunk c =================
    if (c >= NCH) return;
    uint32_t* h16 = smem;                       // 128 dw
    float* part = (float*)(smem + 128);         // 768 f
    const int q = tid >> 8, u = tid & 255;
    const int b = blk;

    uint32_t w[192];
#pragma unroll
    for (int j = 0; j < 192; ++j) w[j] = whh1p[j*512 + tid];

    float h = 0.f, bhr = 0.f, bhz = 0.f, bhn = 0.f, gxr = 0.f, gxz = 0.f, gxn = 0.f;
    const unsigned short* gp = gx1R + (size_t)b*CH*G1n;
    unsigned short* h1p = h1W + (size_t)b*CH*H1n + u;
    if (q == 0){
      if (c > 0) h = hs1[b*H1n + u];
      ((unsigned short*)h16)[u] = f2h(h);
      bhr = bhh1[u]; bhz = bhh1[u+256]; bhn = bhh1[u+512];
      gxr = h2f(gp[u]); gxz = h2f(gp[u+256]); gxn = h2f(gp[u+512]);
    }
    __syncthreads();

    const uint32_t* hh = h16 + (q << 6);
    for (int t = 0; t < CH; ++t){
      float ar0=0,ar1=0,az0=0,az1=0,an0=0,an1=0;
#pragma unroll
      for (int ch = 0; ch < 8; ++ch){
        const uint4 v0 = ((const uint4*)hh)[2*ch+0];
        const uint4 v1 = ((const uint4*)hh)[2*ch+1];
        const int base = ch*8;
        D4(ar0,ar1, base,       v0); D4(ar0,ar1, base+4,     v1);
        D4(az0,az1, base+64,    v0); D4(az0,az1, base+68,    v1);
        D4(an0,an1, base+128,   v0); D4(an0,an1, base+132,   v1);
      }
      if (q == 1){
        part[u]     = ar0 + ar1;
        part[u+256] = az0 + az1;
        part[u+512] = an0 + an1;
      }
      __syncthreads();
      if (q == 0){
        float ghr = ar0+ar1 + part[u]     + bhr;
        float ghz = az0+az1 + part[u+256] + bhz;
        float ghn = an0+an1 + part[u+512] + bhn;
        float r = sigm_(gxr + ghr);
        float z = sigm_(gxz + ghz);
        float n = tanh_(gxn + r*ghn);
        h = n + z*(h - n);                       // (1-z)*n + z*h
        ((unsigned short*)h16)[u] = f2h(h);
        *h1p = f2h(h); h1p += H1n;
        if (t + 1 < CH){
          const unsigned short* gnx = gp + (size_t)(t+1)*G1n;
          gxr = h2f(gnx[u]); gxz = h2f(gnx[u+256]); gxn = h2f(gnx[u+512]);
        }
      }
      __syncthreads();
    }
    if (q == 0) hs1[b*H1n + u] = h;

  } else if (blk < 128){
    // ============ branch B: gemm2 + gru2 for chunk c-1 ============
    if (c < 1) return;
    const int cp = c - 1;
    const int b = blk - 64;
    uint32_t* hl = smem;                              // 4096 dw (16KB) staging
    unsigned short* gx2s = (unsigned short*)(smem + 4096);  // 128*384 fp16 (96KB)

    // ---- gemm2: gx2[b] = h1R[b] @ (W_ih2*s1)^T + b2p, into LDS ----
    const uint32_t* h32 = (const uint32_t*)(h1R + (size_t)b*CH*H1n);
    const int g = tid;
    for (int tile = 0; tile < CH/32; ++tile){
      for (int i = tid; i < 32*128; i += 512) hl[i] = h32[tile*32*128 + i];
      __syncthreads();
      if (g < 384){
        float acc[32];
#pragma unroll
        for (int r = 0; r < 32; ++r) acc[r] = 0.f;
        for (int jc = 0; jc < 16; ++jc){
          uint32_t w8[8];
#pragma unroll
          for (int i = 0; i < 8; ++i) w8[i] = wih2p[(jc*8+i)*384 + g];
#pragma unroll
          for (int r = 0; r < 32; ++r){
            const uint4* hv = (const uint4*)(hl + r*128 + jc*8);
            uint4 v0 = hv[0], v1 = hv[1];
            float a = acc[r];
            a = fdot2(w8[0], v0.x, a); a = fdot2(w8[1], v0.y, a);
            a = fdot2(w8[2], v0.z, a); a = fdot2(w8[3], v0.w, a);
            a = fdot2(w8[4], v1.x, a); a = fdot2(w8[5], v1.y, a);
            a = fdot2(w8[6], v1.z, a); a = fdot2(w8[7], v1.w, a);
            acc[r] = a;
          }
        }
        const float bias = b2p[g];
#pragma unroll
        for (int r = 0; r < 32; ++r)
          gx2s[(tile*32+r)*G2n + g] = f2h(bias + acc[r]);
      }
      __syncthreads();
    }

    // ---- gru2 chunk cp (r2 form; gx read from LDS) ----
    uint32_t* h16 = smem;                      // 64 dw (reuses staging region)
    float* part = (float*)(smem + 64);         // 1152 f
    float* thb  = (float*)(smem + 64 + 1152);  // 128 f
    const int q = tid >> 7, u = tid & 127;

    uint32_t w[48];
#pragma unroll
    for (int j = 0; j < 48; ++j) w[j] = whh2p[j*512 + tid];

    float h = 0.f, m = -3.0e38f;
    float bhr=0,bhz=0,bhn=0, s2=0.f, t2=0.f;
    if (q == 0){
      if (cp > 0){ h = hs2[b*H2n + u]; m = ms2[b*H2n + u]; }
      ((unsigned short*)h16)[u] = f2h(h);
      bhr = bhh2[u]; bhz = bhh2[u+128]; bhn = bhh2[u+256];
      s2 = g2[u]*rsqrtf(v2[u]+1e-5f);
      t2 = be2[u] - m2[u]*s2;
    }
    __syncthreads();

    const uint32_t* hh = h16 + (q << 4);
    for (int t = 0; t < CH; ++t){
      const uint4 v0  = ((const uint4*)hh)[0];
      const uint4 v1  = ((const uint4*)hh)[1];
      const uint4 v2_ = ((const uint4*)hh)[2];
      const uint4 v3  = ((const uint4*)hh)[3];
      float a00=0,a01=0,a10=0,a11=0,a20=0,a21=0;
      D4(a00,a01, 0, v0); D4(a00,a01, 4, v1); D4(a00,a01, 8, v2_); D4(a00,a01,12, v3);
      D4(a10,a11,16, v0); D4(a10,a11,20, v1); D4(a10,a11,24, v2_); D4(a10,a11,28, v3);
      D4(a20,a21,32, v0); D4(a20,a21,36, v1); D4(a20,a21,40, v2_); D4(a20,a21,44, v3);
      if (q > 0){
        int o = (q-1)*384;
        part[o+u]     = a00 + a01;
        part[o+u+128] = a10 + a11;
        part[o+u+256] = a20 + a21;
      }
      __syncthreads();
      if (q == 0){
        float gxr = h2f(gx2s[t*G2n + u]);
        float gxz = h2f(gx2s[t*G2n + u+128]);
        float gxn = h2f(gx2s[t*G2n + u+256]);
        float ghr = a00+a01 + part[u]     + part[384+u]     + part[768+u]     + bhr;
        float ghz = a10+a11 + part[u+128] + part[384+u+128] + part[768+u+128] + bhz;
        float ghn = a20+a21 + part[u+256] + part[384+u+256] + part[768+u+256] + bhn;
        float r = sigm_(gxr + ghr);
        float z = sigm_(gxz + ghz);
        float n = tanh_(gxn + r*ghn);
        h = n + z*(h - n);
        float val = s2*h + t2;               // eval-mode BN2
        m = fmaxf(m, val);                   // global max pool over time
        ((unsigned short*)h16)[u] = f2h(h);
      }
      __syncthreads();
    }
    if (q == 0){ hs2[b*H2n + u] = h; ms2[b*H2n + u] = m; }

    if (cp == NCH-1){                        // last chunk: fused epilogue
      if (q == 0) thb[u] = tanh_(m);
      __syncthreads();
      if (tid < 10){
        float a = fcb[tid];
        for (int k = 0; k < 128; ++k) a += thb[k]*fcw[tid*128+k];
        out[b*10 + tid] = a;
      }
    }

  } else {
    // ================= branch C: gemm1 chunk c+1 =================
    const int c1 = c + 1;
    if (c1 >= NCH) return;
    const int b = blk - 128;
    const bool dual = tid < 256;             // threads 0..255 own cols {tid, tid+512}

    uint32_t w[64];
#pragma unroll
    for (int j = 0; j < 32; ++j) w[j] = wih1p[j*768 + tid];
    float bias0 = bih1[tid], bias1 = 0.f;
    if (dual){
#pragma unroll
      for (int j = 0; j < 32; ++j) w[32+j] = wih1p[j*768 + tid + 512];
      bias1 = bih1[tid + 512];
    }
    const uint32_t* xb = x16 + ((size_t)b*Tn + c1*CH)*32;
    unsigned short* go = gx1W + (size_t)b*CH*G1n;
    for (int r = 0; r < CH; ++r){
      const uint4* xr = (const uint4*)(xb + r*32);
      float a0=0, a1=0, c0=0, c1a=0;
#pragma unroll
      for (int i = 0; i < 8; ++i){
        uint4 v = xr[i];
        a0 = fdot2(w[i*4+0], v.x, a0); a1 = fdot2(w[i*4+1], v.y, a1);
        a0 = fdot2(w[i*4+2], v.z, a0); a1 = fdot2(w[i*4+3], v.w, a1);
        if (dual){
          c0 = fdot2(w[32+i*4+0], v.x, c0); c1a = fdot2(w[32+i*4+1], v.y, c1a);
          c0 = fdot2(w[32+i*4+2], v.z, c0); c1a = fdot2(w[32+i*4+3], v.w, c1a);
        }
      }
      go[(size_t)r*G1n + tid] = f2h(bias0 + a0 + a1);
      if (dual) go[(size_t)r*G1n + tid + 512] = f2h(bias1 + c0 + c1a);
    }
  }
}

// ---------------- launch ----------------

extern "C" void kernel_launch(void* const* d_in, const int* in_sizes, int n_in,
                              void* d_out, int out_size, void* d_ws, size_t ws_size,
                              hipStream_t stream)
{
  const float* x    = (const float*)d_in[0];
  const float* Wih1 = (const float*)d_in[1];
  const float* Whh1 = (const float*)d_in[2];
  const float* bih1 = (const float*)d_in[3];
  const float* bhh1 = (const float*)d_in[4];
  const float* g1   = (const float*)d_in[5];
  const float* be1  = (const float*)d_in[6];
  const float* m1   = (const float*)d_in[7];
  const float* v1   = (const float*)d_in[8];
  const float* Wih2 = (const float*)d_in[9];
  const float* Whh2 = (const float*)d_in[10];
  const float* bih2 = (const float*)d_in[11];
  const float* bhh2 = (const float*)d_in[12];
  const float* g2   = (const float*)d_in[13];
  const float* be2  = (const float*)d_in[14];
  const float* m2   = (const float*)d_in[15];
  const float* v2   = (const float*)d_in[16];
  const float* fcw  = (const float*)d_in[17];
  const float* fcb  = (const float*)d_in[18];
  float* out = (float*)d_out;
  char* ws = (char*)d_ws;

  // workspace layout (bytes) — total ~51.3 MB
  uint32_t* whh1p = (uint32_t*)(ws + 0);          // 393216 B
  uint32_t* wih1p = (uint32_t*)(ws + 393216);     //  98304 B
  uint32_t* wih2p = (uint32_t*)(ws + 491520);     // 196608 B
  uint32_t* whh2p = (uint32_t*)(ws + 688128);     //  98304 B
  float*    b2p   = (float*)   (ws + 786432);     //   1536 B
  float*    hs1   = (float*)   (ws + 787968);     //  65536 B
  float*    hs2   = (float*)   (ws + 853504);     //  32768 B
  float*    ms2   = (float*)   (ws + 886272);     //  32768 B
  uint32_t* x16   = (uint32_t*)(ws + 919040);     // 16777216 B
  unsigned short* gx1a = (unsigned short*)(ws + 17696256);  // 64*128*768*2 = 12582912 B
  unsigned short* gx1b = (unsigned short*)(ws + 30279168);  // 12582912 B
  unsigned short* h1a  = (unsigned short*)(ws + 42862080);  // 64*128*256*2 = 4194304 B
  unsigned short* h1b  = (unsigned short*)(ws + 47056384);  // 4194304 B

  unsigned short* gx1bufs[2] = {gx1a, gx1b};
  unsigned short* h1bufs[2]  = {h1a, h1b};

  pack_x16_kernel<<<2048, 256, 0, stream>>>(x, x16);
  pack_w_kernel<<<770, 256, 0, stream>>>(Wih1, Whh1, Wih2, Whh2, bih2, g1, be1, m1, v1,
                                         wih1p, whh1p, wih2p, whh2p, b2p);
  gemm1_kernel<<<128, 768, 0, stream>>>(x16, wih1p, bih1, gx1bufs[0], 0);
  for (int c = 0; c <= NCH; ++c){
    fused_kernel<<<192, 512, 0, stream>>>(x16, wih1p, bih1,
        gx1bufs[c & 1], gx1bufs[(c + 1) & 1],
        whh1p, bhh1, h1bufs[c & 1], h1bufs[(c + 1) & 1], hs1,
        wih2p, b2p, whh2p, bhh2, g2, be2, m2, v2, fcw, fcb, out,
        hs2, ms2, c);
  }
}